// Round 1
// baseline (99.547 us; speedup 1.0000x reference)
//
#include <hip/hip_runtime.h>

// GSplat renderer: separable-Gaussian formulation.
// weight[n,h,w] = op[n] * exp2(K[n]*dx^2) * exp2(K[n]*dy^2),  K = -inv_s^2/(2 ln2)
// Tables: exG[n][w] = exp2(K*dx^2), eyop[n][h] = op*exp2(K*dy^2).
// Then image contraction is 4 FMAs + 1 mul per (n,pixel) — no transcendentals.

constexpr int HH = 256;
constexpr int WW = 256;
constexpr int PIX = HH * WW;
constexpr float COORD_STEP = 2.0f / 255.0f;  // linspace(-1,1,256) step
constexpr int NSPLIT = 8;                    // N-dimension split for occupancy

__global__ __launch_bounds__(256) void gs_prep(
    const float* __restrict__ means, const float* __restrict__ scales,
    const float* __restrict__ opac, const float* __restrict__ colors,
    float4* __restrict__ params, float4* __restrict__ colpack, int N) {
  int n = blockIdx.x * 256 + threadIdx.x;
  if (n >= N) return;
  float mx = means[3 * n + 0], my = means[3 * n + 1], mz = means[3 * n + 2];
  float scl = fmaxf((scales[3 * n + 0] + scales[3 * n + 1] + scales[3 * n + 2]) * (1.0f / 3.0f), 1e-4f);
  float zs = fabsf(mz) + 1.0f;
  float rzs = 1.0f / zs;
  float px = tanhf(mx * rzs);
  float py = tanhf(my * rzs);
  float sigma = fminf(fmaxf(scl * rzs, 0.02f), 0.5f);
  float inv_s = 1.0f / sigma;
  float K = -0.72134752044f * inv_s * inv_s;  // -0.5/ln2 * inv_s^2
  params[n] = make_float4(px, py, K, opac[n]);
  colpack[n] = make_float4(colors[3 * n + 0], colors[3 * n + 1], colors[3 * n + 2], 0.0f);
}

__global__ __launch_bounds__(256) void gs_tables(
    const float4* __restrict__ params, float* __restrict__ exG,
    float* __restrict__ eyop, int N) {
  int n = blockIdx.x;
  int t = threadIdx.x;  // 0..255, doubles as column index and row index (H==W)
  float4 p = params[n];
  float c = -1.0f + COORD_STEP * (float)t;
  float dx = c - p.x;
  exG[n * WW + t] = exp2f(p.z * dx * dx);
  float dy = c - p.y;
  eyop[n * HH + t] = p.w * exp2f(p.z * dy * dy);
}

// Each block: 4 rows (h4*4 .. h4*4+3) x 256 cols, over an N-chunk.
// Per n: 1 coalesced ex load + uniform (scalar) eyop-quad + color loads,
// then 4 rows x (1 mul + 3 fma + 1 add).
__global__ __launch_bounds__(256) void gs_accum(
    const float* __restrict__ exG, const float4* __restrict__ eyop4,
    const float4* __restrict__ colpack, float* __restrict__ accum, int nchunk) {
  int w = threadIdx.x;
  int h4 = blockIdx.y;
  int n0 = blockIdx.x * nchunk;
  float acc[4][4] = {{0.0f}};  // [row][r,g,b,denom]
  const float* exp_ptr = exG + (size_t)n0 * WW + w;
  for (int i = 0; i < nchunk; ++i) {
    int n = n0 + i;
    float ex = exp_ptr[(size_t)i * WW];
    float4 ey = eyop4[n * (HH / 4) + h4];
    float4 col = colpack[n];
    float eyv[4] = {ey.x, ey.y, ey.z, ey.w};
#pragma unroll
    for (int r = 0; r < 4; ++r) {
      float wt = eyv[r] * ex;
      acc[r][0] = fmaf(wt, col.x, acc[r][0]);
      acc[r][1] = fmaf(wt, col.y, acc[r][1]);
      acc[r][2] = fmaf(wt, col.z, acc[r][2]);
      acc[r][3] += wt;
    }
  }
  int h0 = h4 * 4;
#pragma unroll
  for (int r = 0; r < 4; ++r) {
    int p = (h0 + r) * WW + w;
    atomicAdd(&accum[0 * PIX + p], acc[r][0]);
    atomicAdd(&accum[1 * PIX + p], acc[r][1]);
    atomicAdd(&accum[2 * PIX + p], acc[r][2]);
    atomicAdd(&accum[3 * PIX + p], acc[r][3]);
  }
}

__global__ __launch_bounds__(256) void gs_finalize(
    const float* __restrict__ accum, float* __restrict__ out) {
  int p = blockIdx.x * 256 + threadIdx.x;
  float d = fmaxf(accum[3 * PIX + p], 1e-5f);
  float inv = 1.0f / d;
#pragma unroll
  for (int c = 0; c < 3; ++c) {
    float v = accum[c * PIX + p] * inv;
    out[c * PIX + p] = fminf(fmaxf(v, 0.0f), 1.0f);
  }
}

extern "C" void kernel_launch(void* const* d_in, const int* in_sizes, int n_in,
                              void* d_out, int out_size, void* d_ws, size_t ws_size,
                              hipStream_t stream) {
  const float* means = (const float*)d_in[0];
  // d_in[1] = quats (unused by reference)
  const float* scales = (const float*)d_in[2];
  const float* opac = (const float*)d_in[3];
  const float* colors = (const float*)d_in[4];
  float* out = (float*)d_out;
  int N = in_sizes[0] / 3;  // 2048

  // Workspace layout (floats, 16B-aligned throughout):
  //   params  [N] float4
  //   colpack [N] float4
  //   exG     [N][WW] float
  //   eyop    [N][HH] float
  //   accum   [4][HH][WW] float
  char* ws = (char*)d_ws;
  float4* params = (float4*)ws;
  float4* colpack = (float4*)(ws + (size_t)N * 16);
  float* exG = (float*)(ws + (size_t)N * 32);
  float* eyop = (float*)(ws + (size_t)N * 32 + (size_t)N * WW * 4);
  float* accum = (float*)(ws + (size_t)N * 32 + (size_t)N * (WW + HH) * 4);

  hipMemsetAsync(accum, 0, (size_t)4 * PIX * sizeof(float), stream);
  gs_prep<<<(N + 255) / 256, 256, 0, stream>>>(means, scales, opac, colors, params, colpack, N);
  gs_tables<<<N, 256, 0, stream>>>(params, exG, eyop, N);
  int nchunk = N / NSPLIT;
  gs_accum<<<dim3(NSPLIT, HH / 4), 256, 0, stream>>>(exG, (const float4*)eyop, colpack, accum, nchunk);
  gs_finalize<<<PIX / 256, 256, 0, stream>>>(accum, out);
}

// Round 2
// 48.499 us; speedup vs baseline: 2.0525x; 2.0525x over previous
//
#include <hip/hip_runtime.h>

// GSplat renderer: separable-Gaussian formulation.
// weight[n,h,w] = op[n] * exp2(K[n]*dx^2) * exp2(K[n]*dy^2),  K = -inv_s^2/(2 ln2)
// Tables: exG[n][w] = exp2(K*dx^2), eyop[n][h] = op*exp2(K*dy^2).
// Contraction: per (n,pixel) 5 VALU ops, no transcendentals, no atomics
// (per-N-part partial planes + final reduce).

constexpr int HH = 256;
constexpr int WW = 256;
constexpr int PIX = HH * WW;
constexpr float COORD_STEP = 2.0f / 255.0f;  // linspace(-1,1,256) step

__global__ __launch_bounds__(256) void gs_prep(
    const float* __restrict__ means, const float* __restrict__ scales,
    const float* __restrict__ opac, const float* __restrict__ colors,
    float4* __restrict__ params, float4* __restrict__ colpack, int N) {
  int n = blockIdx.x * 256 + threadIdx.x;
  if (n >= N) return;
  float mx = means[3 * n + 0], my = means[3 * n + 1], mz = means[3 * n + 2];
  float scl = fmaxf((scales[3 * n + 0] + scales[3 * n + 1] + scales[3 * n + 2]) * (1.0f / 3.0f), 1e-4f);
  float zs = fabsf(mz) + 1.0f;
  float rzs = 1.0f / zs;
  float px = tanhf(mx * rzs);
  float py = tanhf(my * rzs);
  float sigma = fminf(fmaxf(scl * rzs, 0.02f), 0.5f);
  float inv_s = 1.0f / sigma;
  float K = -0.72134752044f * inv_s * inv_s;  // -0.5/ln2 * inv_s^2
  params[n] = make_float4(px, py, K, opac[n]);
  colpack[n] = make_float4(colors[3 * n + 0], colors[3 * n + 1], colors[3 * n + 2], 0.0f);
}

__global__ __launch_bounds__(256) void gs_tables(
    const float4* __restrict__ params, float* __restrict__ exG,
    float* __restrict__ eyop, int N) {
  int n = blockIdx.x;
  int t = threadIdx.x;  // 0..255, doubles as column and row index (H==W)
  float4 p = params[n];
  float c = -1.0f + COORD_STEP * (float)t;
  float dx = c - p.x;
  exG[n * WW + t] = exp2f(p.z * dx * dx);
  float dy = c - p.y;
  eyop[n * HH + t] = p.w * exp2f(p.z * dy * dy);
}

// Block = 4 rows x 256 cols x one N-part. Inner loop unrolled x4 for MLP.
// ey-quad and color are wave-uniform -> scalar loads; ex is one coalesced
// dword load per n. Output: plain stores into this part's private planes.
__global__ __launch_bounds__(256) void gs_accum(
    const float* __restrict__ exG, const float4* __restrict__ eyop4,
    const float4* __restrict__ colpack, float* __restrict__ partials, int nchunk) {
  int w = threadIdx.x;
  int h4 = blockIdx.y;
  int part = blockIdx.x;
  int n0 = part * nchunk;
  float acc[4][4] = {{0.0f}};  // [row][r,g,b,denom]
  const float* exp_ptr = exG + (size_t)n0 * WW + w;
  const float4* eyp = eyop4 + (size_t)n0 * (HH / 4) + h4;
  const float4* cp = colpack + n0;

#define GS_ACC(EX, EY, COL)                      \
  {                                              \
    float wt0 = (EY).x * (EX);                   \
    acc[0][0] = fmaf(wt0, (COL).x, acc[0][0]);   \
    acc[0][1] = fmaf(wt0, (COL).y, acc[0][1]);   \
    acc[0][2] = fmaf(wt0, (COL).z, acc[0][2]);   \
    acc[0][3] += wt0;                            \
    float wt1 = (EY).y * (EX);                   \
    acc[1][0] = fmaf(wt1, (COL).x, acc[1][0]);   \
    acc[1][1] = fmaf(wt1, (COL).y, acc[1][1]);   \
    acc[1][2] = fmaf(wt1, (COL).z, acc[1][2]);   \
    acc[1][3] += wt1;                            \
    float wt2 = (EY).z * (EX);                   \
    acc[2][0] = fmaf(wt2, (COL).x, acc[2][0]);   \
    acc[2][1] = fmaf(wt2, (COL).y, acc[2][1]);   \
    acc[2][2] = fmaf(wt2, (COL).z, acc[2][2]);   \
    acc[2][3] += wt2;                            \
    float wt3 = (EY).w * (EX);                   \
    acc[3][0] = fmaf(wt3, (COL).x, acc[3][0]);   \
    acc[3][1] = fmaf(wt3, (COL).y, acc[3][1]);   \
    acc[3][2] = fmaf(wt3, (COL).z, acc[3][2]);   \
    acc[3][3] += wt3;                            \
  }

  for (int i = 0; i < nchunk; i += 4) {
    float ex0 = exp_ptr[0 * WW];
    float ex1 = exp_ptr[1 * WW];
    float ex2 = exp_ptr[2 * WW];
    float ex3 = exp_ptr[3 * WW];
    float4 ey0 = eyp[0 * (HH / 4)];
    float4 ey1 = eyp[1 * (HH / 4)];
    float4 ey2 = eyp[2 * (HH / 4)];
    float4 ey3 = eyp[3 * (HH / 4)];
    float4 c0 = cp[0];
    float4 c1 = cp[1];
    float4 c2 = cp[2];
    float4 c3 = cp[3];
    GS_ACC(ex0, ey0, c0);
    GS_ACC(ex1, ey1, c1);
    GS_ACC(ex2, ey2, c2);
    GS_ACC(ex3, ey3, c3);
    exp_ptr += 4 * WW;
    eyp += HH;  // 4 * (HH/4) float4s
    cp += 4;
  }
#undef GS_ACC

  float* pb = partials + (size_t)part * 4 * PIX;
  int h0 = h4 * 4;
#pragma unroll
  for (int r = 0; r < 4; ++r) {
#pragma unroll
    for (int c = 0; c < 4; ++c) {
      pb[c * PIX + (h0 + r) * WW + w] = acc[r][c];
    }
  }
}

__global__ __launch_bounds__(256) void gs_finalize(
    const float4* __restrict__ partials4, float* __restrict__ out, int parts) {
  int t = blockIdx.x * 256 + threadIdx.x;  // float4-group index, PIX/4 total
  float4 s0 = make_float4(0.f, 0.f, 0.f, 0.f);
  float4 s1 = s0, s2 = s0, s3 = s0;
  const float4* bp = partials4 + t;
  for (int p = 0; p < parts; ++p) {
    float4 a = bp[0 * (PIX / 4)];
    float4 b = bp[1 * (PIX / 4)];
    float4 c = bp[2 * (PIX / 4)];
    float4 d = bp[3 * (PIX / 4)];
    s0.x += a.x; s0.y += a.y; s0.z += a.z; s0.w += a.w;
    s1.x += b.x; s1.y += b.y; s1.z += b.z; s1.w += b.w;
    s2.x += c.x; s2.y += c.y; s2.z += c.z; s2.w += c.w;
    s3.x += d.x; s3.y += d.y; s3.z += d.z; s3.w += d.w;
    bp += 4 * (PIX / 4);
  }
  float ix = 1.0f / fmaxf(s3.x, 1e-5f);
  float iy = 1.0f / fmaxf(s3.y, 1e-5f);
  float iz = 1.0f / fmaxf(s3.z, 1e-5f);
  float iw = 1.0f / fmaxf(s3.w, 1e-5f);
  float4* out4 = (float4*)out;
#define GS_FIN(S, CH)                                              \
  out4[(CH) * (PIX / 4) + t] = make_float4(                        \
      fminf(fmaxf((S).x * ix, 0.0f), 1.0f),                        \
      fminf(fmaxf((S).y * iy, 0.0f), 1.0f),                        \
      fminf(fmaxf((S).z * iz, 0.0f), 1.0f),                        \
      fminf(fmaxf((S).w * iw, 0.0f), 1.0f));
  GS_FIN(s0, 0)
  GS_FIN(s1, 1)
  GS_FIN(s2, 2)
#undef GS_FIN
}

extern "C" void kernel_launch(void* const* d_in, const int* in_sizes, int n_in,
                              void* d_out, int out_size, void* d_ws, size_t ws_size,
                              hipStream_t stream) {
  const float* means = (const float*)d_in[0];
  // d_in[1] = quats (unused by reference)
  const float* scales = (const float*)d_in[2];
  const float* opac = (const float*)d_in[3];
  const float* colors = (const float*)d_in[4];
  float* out = (float*)d_out;
  int N = in_sizes[0] / 3;  // 2048

  // Workspace layout (16B-aligned):
  //   params   [N] float4
  //   colpack  [N] float4
  //   exG      [N][WW] float
  //   eyop     [N][HH] float
  //   partials [parts][4][PIX] float
  char* ws = (char*)d_ws;
  float4* params = (float4*)ws;
  float4* colpack = (float4*)(ws + (size_t)N * 16);
  float* exG = (float*)(ws + (size_t)N * 32);
  float* eyop = (float*)(ws + (size_t)N * 32 + (size_t)N * WW * 4);
  size_t base = (size_t)N * 32 + (size_t)N * (WW + HH) * 4;
  float* partials = (float*)(ws + base);

  // Pick the largest power-of-2 part count (<=32) whose partial planes fit ws.
  int parts = 1;
  for (int p = 32; p >= 1; p >>= 1) {
    if (base + (size_t)p * 4 * PIX * 4 <= ws_size) { parts = p; break; }
  }
  int nchunk = N / parts;

  gs_prep<<<(N + 255) / 256, 256, 0, stream>>>(means, scales, opac, colors, params, colpack, N);
  gs_tables<<<N, 256, 0, stream>>>(params, exG, eyop, N);
  gs_accum<<<dim3(parts, HH / 4), 256, 0, stream>>>(exG, (const float4*)eyop, colpack, partials, nchunk);
  gs_finalize<<<PIX / 4 / 256, 256, 0, stream>>>((const float4*)partials, out, parts);
}